// Round 4
// baseline (72.058 us; speedup 1.0000x reference)
//
#include <hip/hip_runtime.h>

#define B_ 2
#define A_ 16384
#define C_ 15
#define G_ 16
#define D2Rf 0.017453292519943295f
#define ENC_HALF 0xBF000000u   // enc(0.5f)
#define ENC_04   0xBECCCCCDu   // enc(0.4f)
#define NBLK 128               // (B_*A_)/256; 64 blocks per image

__device__ __forceinline__ unsigned enc_f32(float f) {
    unsigned u = __float_as_uint(f);
    return u ^ ((u >> 31) ? 0xFFFFFFFFu : 0x80000000u);
}

// ---------------------------------------------------------------------------
// Rotated IoU, replicating the JAX reference op-for-op in fp32.
// (verified absmax 0.0 in R1-R3)
// ---------------------------------------------------------------------------
__device__ __forceinline__ void rect_corners5(const float* b, float X[4], float Y[4],
                                              float* cth, float* sth) {
    float th = b[4] * D2Rf;
    float c = cosf(th), s = sinf(th);
    *cth = c; *sth = s;
    const float SX[4] = {-1.f, 1.f, 1.f, -1.f};
    const float SY[4] = {-1.f, -1.f, 1.f, 1.f};
    float hw = 0.5f * b[2], hh = 0.5f * b[3];
#pragma unroll
    for (int i = 0; i < 4; ++i) {
        float dx = hw * SX[i];
        float dy = hh * SY[i];
        X[i] = b[0] + dx * c - dy * s;
        Y[i] = b[1] + dx * s + dy * c;
    }
}

__device__ float rotated_iou_pair(const float* ab, const float* gb) {
    float ax[4], ay[4], gx[4], gy[4];
    float cA, sA, cG, sG;
    rect_corners5(ab, ax, ay, &cA, &sA);
    rect_corners5(gb, gx, gy, &cG, &sG);

    float rx[24], ry[24];
    unsigned msk = 0u;

#pragma unroll
    for (int i = 0; i < 4; ++i) {
        float dx = ax[i] - gb[0], dy = ay[i] - gb[1];
        float lx = dx * cG + dy * sG;
        float ly = -dx * sG + dy * cG;
        bool in = (fabsf(lx) <= 0.5f * gb[2] + 1e-4f) && (fabsf(ly) <= 0.5f * gb[3] + 1e-4f);
        rx[i] = ax[i]; ry[i] = ay[i];
        if (in) msk |= (1u << i);
    }
#pragma unroll
    for (int i = 0; i < 4; ++i) {
        float dx = gx[i] - ab[0], dy = gy[i] - ab[1];
        float lx = dx * cA + dy * sA;
        float ly = -dx * sA + dy * cA;
        bool in = (fabsf(lx) <= 0.5f * ab[2] + 1e-4f) && (fabsf(ly) <= 0.5f * ab[3] + 1e-4f);
        rx[4 + i] = gx[i]; ry[4 + i] = gy[i];
        if (in) msk |= (1u << (4 + i));
    }
#pragma unroll
    for (int i = 0; i < 4; ++i) {
        float p0x = ax[i], p0y = ay[i];
        float p1x = ax[(i + 1) & 3], p1y = ay[(i + 1) & 3];
        float d1x = p1x - p0x, d1y = p1y - p0y;
#pragma unroll
        for (int j = 0; j < 4; ++j) {
            float q0x = gx[j], q0y = gy[j];
            float q1x = gx[(j + 1) & 3], q1y = gy[(j + 1) & 3];
            float d2x = q1x - q0x, d2y = q1y - q0y;
            float rrx = q0x - p0x, rry = q0y - p0y;
            float den = d1x * d2y - d1y * d2x;
            float safe = (fabsf(den) < 1e-8f) ? 1.f : den;
            float t = (rrx * d2y - rry * d2x) / safe;
            float u = (rrx * d1y - rry * d1x) / safe;
            bool ok = (fabsf(den) >= 1e-8f) && (t >= 0.f) && (t <= 1.f) && (u >= 0.f) && (u <= 1.f);
            int k = 8 + i * 4 + j;
            rx[k] = p0x + t * d1x;
            ry[k] = p0y + t * d1y;
            if (ok) msk |= (1u << k);
        }
    }

    int cnt = __popc(msk);
    float sx = 0.f, sy = 0.f;
#pragma unroll
    for (int k = 0; k < 24; ++k)
        if ((msk >> k) & 1u) { sx += rx[k]; sy += ry[k]; }
    float cnf = fmaxf((float)cnt, 1.f);
    float cenx = sx / cnf, ceny = sy / cnf;

    float ang[24];
#pragma unroll
    for (int k = 0; k < 24; ++k) {
        if ((msk >> k) & 1u) {
            rx[k] -= cenx; ry[k] -= ceny;
            ang[k] = atan2f(ry[k], rx[k]);
        } else {
            rx[k] = 0.f; ry[k] = 0.f;
            ang[k] = 1e9f;
        }
    }

    int rnk[24];
#pragma unroll
    for (int k = 0; k < 24; ++k) {
        int r = 0;
#pragma unroll
        for (int j = 0; j < 24; ++j)
            r += (ang[j] < ang[k]) || (ang[j] == ang[k] && j < k);
        rnk[k] = r;
    }

    float ssum = 0.f;
#pragma unroll
    for (int k = 0; k < 24; ++k) {
        if ((msk >> k) & 1u) {
            int tgt = (rnk[k] + 1 == cnt) ? 0 : rnk[k] + 1;
            float qx = 0.f, qy = 0.f;
#pragma unroll
            for (int j = 0; j < 24; ++j) {
                if (((msk >> j) & 1u) && rnk[j] == tgt) { qx = rx[j]; qy = ry[j]; }
            }
            ssum += rx[k] * qy - ry[k] * qx;
        }
    }
    float inter = (cnt >= 3) ? 0.5f * fabsf(ssum) : 0.f;
    float uni = ab[2] * ab[3] + gb[2] * gb[3] - inter;
    return inter / fmaxf(uni, 1e-8f);
}

// ---------------------------------------------------------------------------
// Kernel 1 (fused gate + heavy): per-anchor square gate, wave-local dense
// compaction, rotated IoU on passing pairs only. Never materializes the iou
// matrix: row max/argmax reduced online into packed u64 per anchor, column
// max/argmax into 32 LDS cells per block. All combines are max on packed
// monotone keys (assoc/comm -> deterministic regardless of list order).
// ---------------------------------------------------------------------------
__global__ void fused_kernel(const float* __restrict__ anc,
                             const float* __restrict__ ann,
                             unsigned long long* __restrict__ rowMaxArg,
                             unsigned long long* __restrict__ partials) {
    __shared__ float aLds[256][5];
    __shared__ float annLds[B_ * G_][6];
    __shared__ unsigned wlist[4][1024];
    __shared__ unsigned wcnt[4];
    __shared__ unsigned long long rowkey[256];
    __shared__ unsigned long long cells[32];

    const int tid = threadIdx.x;
    const int t = blockIdx.x * 256 + tid;       // global anchor id
    const int b = blockIdx.x >> 6;              // 64 blocks per image
    const int wid = tid >> 6, lane = tid & 63;

    if (tid < 4) wcnt[tid] = 0u;
    if (tid < 32) cells[tid] = 0ull;
    if (tid < B_ * G_) {
        const float* g6 = ann + (size_t)tid * 6;
#pragma unroll
        for (int k = 0; k < 6; ++k) annLds[tid][k] = g6[k];
    }
    const float* ab = anc + (size_t)t * 5;
    float a0 = ab[0], a1 = ab[1], a2 = ab[2], a3 = ab[3], a4 = ab[4];
    aLds[tid][0] = a0; aLds[tid][1] = a1; aLds[tid][2] = a2;
    aLds[tid][3] = a3; aLds[tid][4] = a4;
    __syncthreads();

    // ---- gate: square IoU > 0.1, plus light row-max seed ----
    float sa = 0.5f * fmaxf(a2, a3);
    unsigned passmask = 0u;
    unsigned long long rk = 0ull;
#pragma unroll
    for (int g = 0; g < G_; ++g) {
        const float* gb = annLds[b * G_ + g];
        float v;
        if (gb[5] == -1.0f) {
            v = -1.0f;
        } else {
            float sb = 0.5f * fmaxf(gb[2], gb[3]);
            float iw = fminf(a0 + sa, gb[0] + sb) - fmaxf(a0 - sa, gb[0] - sb);
            iw = fmaxf(iw, 0.f);
            float ih = fminf(a1 + sa, gb[1] + sb) - fmaxf(a1 - sa, gb[1] - sb);
            ih = fmaxf(ih, 0.f);
            float inter = iw * ih;
            float uni = 4.f * sa * sa + 4.f * sb * sb - inter;
            float ind = inter / fmaxf(uni, 1e-8f);
            if (ind > 0.1f) passmask |= (1u << g);
            v = 0.f;  // placeholder <= heavy value (IoU >= 0), same tiebreak bits
        }
        unsigned long long key =
            ((unsigned long long)enc_f32(v) << 32) | (unsigned)(G_ - 1 - g);
        if (key > rk) rk = key;
    }
    rowkey[tid] = rk;

    // ---- wave-local compaction into LDS list ----
    unsigned cnt = __popc(passmask);
    unsigned base = 0;
    if (cnt) base = atomicAdd(&wcnt[wid], cnt);
    unsigned p = base;
#pragma unroll
    for (int g = 0; g < G_; ++g) {
        if ((passmask >> g) & 1u) wlist[wid][p++] = ((unsigned)tid << 4) | (unsigned)g;
    }
    __syncthreads();

    // ---- dense heavy loop over this wave's list ----
    unsigned n = wcnt[wid];
    for (unsigned i = lane; i < n; i += 64) {
        unsigned pid = wlist[wid][i];
        int lt = (int)(pid >> 4), g = (int)(pid & 15u);
        float abL[5], gbL[6];
#pragma unroll
        for (int k = 0; k < 5; ++k) abL[k] = aLds[lt][k];
#pragma unroll
        for (int k = 0; k < 6; ++k) gbL[k] = annLds[b * G_ + g][k];
        float v = rotated_iou_pair(abL, gbL);
        unsigned long long ev = (unsigned long long)enc_f32(v);
        atomicMax(&rowkey[lt], (ev << 32) | (unsigned)(G_ - 1 - g));
        int aIdx = (blockIdx.x * 256 + lt) & (A_ - 1);
        atomicMax(&cells[b * G_ + g], (ev << 32) | (0xFFFFFFFFu - (unsigned)aIdx));
    }
    __syncthreads();

    rowMaxArg[t] = rowkey[tid];
    if (tid < 32) partials[(size_t)blockIdx.x * 32 + tid] = cells[tid];
}

// ---------------------------------------------------------------------------
// Kernel 2: reduce per-block colmax partials + default candidate (0.0, a=0).
// For a valid gt every non-heavy column entry is exactly 0.0, so the column
// argmax is max(best heavy pair, (0.0, anchor 0)).
// ---------------------------------------------------------------------------
__global__ void colfinal_kernel(const unsigned long long* __restrict__ partials,
                                unsigned long long* __restrict__ packed) {
    __shared__ unsigned long long red[256];
    int cell = threadIdx.x & 31, chunk = threadIdx.x >> 5;  // 8 chunks x 16 blocks
    unsigned long long m = 0ull;
    for (int blk = chunk * (NBLK / 8); blk < (chunk + 1) * (NBLK / 8); ++blk) {
        unsigned long long v = partials[(size_t)blk * 32 + cell];
        if (v > m) m = v;
    }
    red[threadIdx.x] = m;
    __syncthreads();
    if (threadIdx.x < 32) {
        unsigned long long mm =
            ((unsigned long long)enc_f32(0.0f) << 32) | 0xFFFFFFFFu;  // (0.0, a=0)
        for (int c = 0; c < 8; ++c) {
            unsigned long long v = red[c * 32 + threadIdx.x];
            if (v > mm) mm = v;
        }
        packed[threadIdx.x] = mm;
    }
}

// ---------------------------------------------------------------------------
// Kernel 3: per-anchor loss; thresholds compared in encoded domain
// (enc is monotone). Block partial sums.
// ---------------------------------------------------------------------------
__global__ void loss_kernel(const float* __restrict__ cls_p,
                            const float* __restrict__ reg_p,
                            const float* __restrict__ anc,
                            const float* __restrict__ ann,
                            const unsigned long long* __restrict__ rowMaxArg,
                            const unsigned long long* __restrict__ packed,
                            float* __restrict__ pcls,
                            float* __restrict__ preg,
                            int* __restrict__ pnp) {
    int t = blockIdx.x * blockDim.x + threadIdx.x;  // over B_*A_
    int b = t >> 14;
    int a = t & (A_ - 1);

    unsigned long long rk = rowMaxArg[t];
    unsigned eh = (unsigned)(rk >> 32);             // enc(row max)
    int arg = (G_ - 1) - (int)(rk & 0xFu);          // first-g argmax

    // forced flag: some gt's column-argmax is this anchor, with colmax < 0.5
    bool forcedf = false;
#pragma unroll
    for (int g = 0; g < G_; ++g) {
        unsigned long long pk = packed[b * G_ + g];     // uniform -> scalar
        float lab = ann[((size_t)b * G_ + g) * 6 + 5];  // uniform -> scalar
        unsigned hi = (unsigned)(pk >> 32);
        unsigned ai = 0xFFFFFFFFu - (unsigned)pk;
        forcedf |= (lab != -1.0f) && (hi < ENC_HALF) && (ai == (unsigned)a);
    }

    bool pos = (eh >= ENC_HALF) || forcedf;
    const float* g6 = ann + ((size_t)b * G_ + arg) * 6;
    int cls = (int)g6[5];

    float csum = 0.f;
    if (pos || eh < ENC_04) {
        const float* pr = cls_p + (size_t)t * C_;
#pragma unroll
        for (int c = 0; c < C_; ++c) {
            float tgt = (pos && c == cls) ? 1.f : 0.f;
            float p = fminf(fmaxf(pr[c], 1e-4f), 1.f - 1e-4f);
            float af = (tgt == 1.f) ? 0.25f : 0.75f;
            float x = (tgt == 1.f) ? (1.f - p) : p;
            float fw = af * x * x;
            float bce = -(tgt * logf(p + 1e-6f) + (1.f - tgt) * logf(1.f - p + 1e-6f));
            csum += fw * bce;
        }
    }

    float rsum = 0.f;
    if (pos) {
        const float* ex = anc + (size_t)t * 5;
        const float* rp = reg_p + (size_t)t * 5;
        float ew = fmaxf(ex[2], 1.f), eh2 = fmaxf(ex[3], 1.f);
        float gw = fmaxf(g6[2], 1.f), gh = fmaxf(g6[3], 1.f);
        float tg[5];
        tg[0] = 10.f * (g6[0] - ex[0]) / ew;
        tg[1] = 10.f * (g6[1] - ex[1]) / eh2;
        tg[2] = 10.f * logf(gw / ew);
        tg[3] = 5.f * logf(gh / eh2);
        tg[4] = 15.f * (tanf(g6[4] * D2Rf) - tanf(ex[4] * D2Rf));
        const float BETAf = (float)(1.0 / 9.0);
#pragma unroll
        for (int i = 0; i < 5; ++i) {
            float d = fabsf(rp[i] - tg[i]);
            rsum += (d < BETAf) ? 0.5f * d * d / BETAf : d - 0.5f * BETAf;
        }
    }

    __shared__ float sc[256], sr[256];
    __shared__ int sp[256];
    sc[threadIdx.x] = csum; sr[threadIdx.x] = rsum; sp[threadIdx.x] = pos ? 1 : 0;
    __syncthreads();
    for (int s = 128; s > 0; s >>= 1) {
        if (threadIdx.x < s) {
            sc[threadIdx.x] += sc[threadIdx.x + s];
            sr[threadIdx.x] += sr[threadIdx.x + s];
            sp[threadIdx.x] += sp[threadIdx.x + s];
        }
        __syncthreads();
    }
    if (threadIdx.x == 0) {
        pcls[blockIdx.x] = sc[0];
        preg[blockIdx.x] = sr[0];
        pnp[blockIdx.x] = sp[0];
    }
}

// ---------------------------------------------------------------------------
// Kernel 4: final combine (deterministic ordered sum)
// ---------------------------------------------------------------------------
__global__ void final_kernel(const float* __restrict__ ann,
                             const float* __restrict__ pcls,
                             const float* __restrict__ preg,
                             const int* __restrict__ pnp,
                             float* __restrict__ out) {
    if (threadIdx.x == 0 && blockIdx.x == 0) {
        const int BPI = NBLK / B_;  // blocks per image = 64
        float cl[B_], rl[B_];
        for (int b = 0; b < B_; ++b) {
            float cs = 0.f, rs = 0.f; int np = 0;
            for (int i = 0; i < BPI; ++i) {
                cs += pcls[b * BPI + i];
                rs += preg[b * BPI + i];
                np += pnp[b * BPI + i];
            }
            bool has = false;
            for (int g = 0; g < G_; ++g)
                if (ann[((size_t)b * G_ + g) * 6 + 5] != -1.0f) has = true;
            float c_ = cs / fmaxf((float)np, 1.f);
            int d5 = np * 5; if (d5 < 1) d5 = 1;
            float r_ = (np > 0) ? rs / (float)d5 : 0.f;
            cl[b] = has ? c_ : 0.f;
            rl[b] = has ? r_ : 0.f;
        }
        float cm = 0.f, rm = 0.f;
        for (int b = 0; b < B_; ++b) { cm += cl[b]; rm += rl[b]; }
        out[0] = cm / (float)B_;
        out[1] = rm / (float)B_;
    }
}

// ---------------------------------------------------------------------------
extern "C" void kernel_launch(void* const* d_in, const int* in_sizes, int n_in,
                              void* d_out, int out_size, void* d_ws, size_t ws_size,
                              hipStream_t stream) {
    const float* cls_p = (const float*)d_in[0];   // (B,A,C)
    const float* reg_p = (const float*)d_in[1];   // (B,A,5)
    const float* anc   = (const float*)d_in[2];   // (B,A,5)
    const float* ann   = (const float*)d_in[3];   // (B,G,6)
    float* out = (float*)d_out;

    // workspace layout (everything fully rewritten each call)
    char* ws = (char*)d_ws;
    unsigned long long* packed    = (unsigned long long*)ws;          // 32 * 8B
    unsigned long long* partials  = (unsigned long long*)(ws + 256);  // NBLK*32*8 = 32 KB
    unsigned long long* rowMaxArg = (unsigned long long*)(ws + 256 + NBLK * 32 * 8);  // 256 KB
    float* pcls = (float*)(rowMaxArg + (size_t)B_ * A_);              // 128
    float* preg = pcls + NBLK;
    int*   pnp  = (int*)(preg + NBLK);

    fused_kernel<<<NBLK, 256, 0, stream>>>(anc, ann, rowMaxArg, partials);
    colfinal_kernel<<<1, 256, 0, stream>>>(partials, packed);
    loss_kernel<<<NBLK, 256, 0, stream>>>(cls_p, reg_p, anc, ann,
                                          rowMaxArg, packed, pcls, preg, pnp);
    final_kernel<<<1, 64, 0, stream>>>(ann, pcls, preg, pnp, out);
}

// Round 5
// 47.567 us; speedup vs baseline: 1.5149x; 1.5149x over previous
//
#include <hip/hip_runtime.h>

#define B_ 2
#define A_ 16384
#define C_ 15
#define G_ 16
#define D2Rf 0.017453292519943295f
#define ENC_HALF 0xBF000000u   // enc(0.5f)
#define ENC_04   0xBECCCCCDu   // enc(0.4f)
#define NBLK 128               // gate blocks = (B_*A_)/256; 64 per image
#define HB_ 256                // heavy blocks (2 per gate segment)
#define SEGCAP 4096            // worklist capacity per gate segment

__device__ __forceinline__ unsigned enc_f32(float f) {
    unsigned u = __float_as_uint(f);
    return u ^ ((u >> 31) ? 0xFFFFFFFFu : 0x80000000u);
}

// ---------------------------------------------------------------------------
// Rotated IoU, replicating the JAX reference op-for-op in fp32.
// (verified absmax 0.0 in R1-R4)
// ---------------------------------------------------------------------------
__device__ __forceinline__ void rect_corners5(const float* b, float X[4], float Y[4],
                                              float* cth, float* sth) {
    float th = b[4] * D2Rf;
    float c = cosf(th), s = sinf(th);
    *cth = c; *sth = s;
    const float SX[4] = {-1.f, 1.f, 1.f, -1.f};
    const float SY[4] = {-1.f, -1.f, 1.f, 1.f};
    float hw = 0.5f * b[2], hh = 0.5f * b[3];
#pragma unroll
    for (int i = 0; i < 4; ++i) {
        float dx = hw * SX[i];
        float dy = hh * SY[i];
        X[i] = b[0] + dx * c - dy * s;
        Y[i] = b[1] + dx * s + dy * c;
    }
}

__device__ float rotated_iou_pair(const float* ab, const float* gb) {
    float ax[4], ay[4], gx[4], gy[4];
    float cA, sA, cG, sG;
    rect_corners5(ab, ax, ay, &cA, &sA);
    rect_corners5(gb, gx, gy, &cG, &sG);

    float rx[24], ry[24];
    unsigned msk = 0u;

#pragma unroll
    for (int i = 0; i < 4; ++i) {
        float dx = ax[i] - gb[0], dy = ay[i] - gb[1];
        float lx = dx * cG + dy * sG;
        float ly = -dx * sG + dy * cG;
        bool in = (fabsf(lx) <= 0.5f * gb[2] + 1e-4f) && (fabsf(ly) <= 0.5f * gb[3] + 1e-4f);
        rx[i] = ax[i]; ry[i] = ay[i];
        if (in) msk |= (1u << i);
    }
#pragma unroll
    for (int i = 0; i < 4; ++i) {
        float dx = gx[i] - ab[0], dy = gy[i] - ab[1];
        float lx = dx * cA + dy * sA;
        float ly = -dx * sA + dy * cA;
        bool in = (fabsf(lx) <= 0.5f * ab[2] + 1e-4f) && (fabsf(ly) <= 0.5f * ab[3] + 1e-4f);
        rx[4 + i] = gx[i]; ry[4 + i] = gy[i];
        if (in) msk |= (1u << (4 + i));
    }
#pragma unroll
    for (int i = 0; i < 4; ++i) {
        float p0x = ax[i], p0y = ay[i];
        float p1x = ax[(i + 1) & 3], p1y = ay[(i + 1) & 3];
        float d1x = p1x - p0x, d1y = p1y - p0y;
#pragma unroll
        for (int j = 0; j < 4; ++j) {
            float q0x = gx[j], q0y = gy[j];
            float q1x = gx[(j + 1) & 3], q1y = gy[(j + 1) & 3];
            float d2x = q1x - q0x, d2y = q1y - q0y;
            float rrx = q0x - p0x, rry = q0y - p0y;
            float den = d1x * d2y - d1y * d2x;
            float safe = (fabsf(den) < 1e-8f) ? 1.f : den;
            float t = (rrx * d2y - rry * d2x) / safe;
            float u = (rrx * d1y - rry * d1x) / safe;
            bool ok = (fabsf(den) >= 1e-8f) && (t >= 0.f) && (t <= 1.f) && (u >= 0.f) && (u <= 1.f);
            int k = 8 + i * 4 + j;
            rx[k] = p0x + t * d1x;
            ry[k] = p0y + t * d1y;
            if (ok) msk |= (1u << k);
        }
    }

    int cnt = __popc(msk);
    float sx = 0.f, sy = 0.f;
#pragma unroll
    for (int k = 0; k < 24; ++k)
        if ((msk >> k) & 1u) { sx += rx[k]; sy += ry[k]; }
    float cnf = fmaxf((float)cnt, 1.f);
    float cenx = sx / cnf, ceny = sy / cnf;

    float ang[24];
#pragma unroll
    for (int k = 0; k < 24; ++k) {
        if ((msk >> k) & 1u) {
            rx[k] -= cenx; ry[k] -= ceny;
            ang[k] = atan2f(ry[k], rx[k]);
        } else {
            rx[k] = 0.f; ry[k] = 0.f;
            ang[k] = 1e9f;
        }
    }

    int rnk[24];
#pragma unroll
    for (int k = 0; k < 24; ++k) {
        int r = 0;
#pragma unroll
        for (int j = 0; j < 24; ++j)
            r += (ang[j] < ang[k]) || (ang[j] == ang[k] && j < k);
        rnk[k] = r;
    }

    float ssum = 0.f;
#pragma unroll
    for (int k = 0; k < 24; ++k) {
        if ((msk >> k) & 1u) {
            int tgt = (rnk[k] + 1 == cnt) ? 0 : rnk[k] + 1;
            float qx = 0.f, qy = 0.f;
#pragma unroll
            for (int j = 0; j < 24; ++j) {
                if (((msk >> j) & 1u) && rnk[j] == tgt) { qx = rx[j]; qy = ry[j]; }
            }
            ssum += rx[k] * qy - ry[k] * qx;
        }
    }
    float inter = (cnt >= 3) ? 0.5f * fabsf(ssum) : 0.f;
    float uni = ab[2] * ab[3] + gb[2] * gb[3] - inter;
    return inter / fmaxf(uni, 1e-8f);
}

// ---------------------------------------------------------------------------
// Kernel 1: gate — square-IoU gate, light rowkey, per-block compacted segment
// (fixed offsets + exact count: no global atomics, nothing to memset).
// ---------------------------------------------------------------------------
__global__ void gate_kernel(const float* __restrict__ anc,
                            const float* __restrict__ ann,
                            unsigned long long* __restrict__ rowMaxArg,
                            unsigned* __restrict__ wl,
                            unsigned* __restrict__ segcnt) {
    const int tid = threadIdx.x;
    const int t = blockIdx.x * 256 + tid;   // global anchor id
    const int b = blockIdx.x >> 6;          // 64 blocks per image

    const float* ab = anc + (size_t)t * 5;
    float a0 = ab[0], a1 = ab[1], a2 = ab[2], a3 = ab[3];
    float sa = 0.5f * fmaxf(a2, a3);

    unsigned passmask = 0u;
    unsigned long long rk = 0ull;
#pragma unroll
    for (int g = 0; g < G_; ++g) {
        const float* gb = ann + ((size_t)b * G_ + g) * 6;  // broadcast loads
        float v;
        if (gb[5] == -1.0f) {
            v = -1.0f;
        } else {
            float sb = 0.5f * fmaxf(gb[2], gb[3]);
            float iw = fminf(a0 + sa, gb[0] + sb) - fmaxf(a0 - sa, gb[0] - sb);
            iw = fmaxf(iw, 0.f);
            float ih = fminf(a1 + sa, gb[1] + sb) - fmaxf(a1 - sa, gb[1] - sb);
            ih = fmaxf(ih, 0.f);
            float inter = iw * ih;
            float uni = 4.f * sa * sa + 4.f * sb * sb - inter;
            float ind = inter / fmaxf(uni, 1e-8f);
            if (ind > 0.1f) passmask |= (1u << g);
            v = 0.f;  // placeholder <= any heavy IoU, same tiebreak bits
        }
        unsigned long long key =
            ((unsigned long long)enc_f32(v) << 32) | (unsigned)(G_ - 1 - g);
        if (key > rk) rk = key;
    }
    rowMaxArg[t] = rk;

    // block-wide inclusive scan of pass counts -> segment offsets
    int cnt = __popc(passmask);
    __shared__ int ss[256];
    ss[tid] = cnt;
    __syncthreads();
    for (int s = 1; s < 256; s <<= 1) {
        int v = (tid >= s) ? ss[tid - s] : 0;
        __syncthreads();
        ss[tid] += v;
        __syncthreads();
    }
    unsigned p = (unsigned)(ss[tid] - cnt);
    unsigned* seg = wl + (size_t)blockIdx.x * SEGCAP;
#pragma unroll
    for (int g = 0; g < G_; ++g) {
        if ((passmask >> g) & 1u) seg[p++] = ((unsigned)tid << 4) | (unsigned)g;
    }
    if (tid == 0) segcnt[blockIdx.x] = (unsigned)ss[255];
}

// ---------------------------------------------------------------------------
// Kernel 2: heavy — dense rotated IoU over segments. 2 blocks per segment
// (interleaved items), 512 threads, VGPR cap 256 so the clip's ~100-float
// working set stays in registers. Row max via scattered global atomicMax
// (assoc/comm max on monotone packed keys -> deterministic); col max via
// per-block LDS cells -> partials.
// ---------------------------------------------------------------------------
__global__ void __launch_bounds__(512, 2)
heavy_kernel(const float* __restrict__ anc,
             const float* __restrict__ ann,
             const unsigned* __restrict__ wl,
             const unsigned* __restrict__ segcnt,
             unsigned long long* __restrict__ rowMaxArg,
             unsigned long long* __restrict__ partials) {
    __shared__ unsigned long long cells[32];
    if (threadIdx.x < 32) cells[threadIdx.x] = 0ull;
    __syncthreads();

    const int segi = blockIdx.x >> 1, half = blockIdx.x & 1;
    const int b = segi >> 6;
    const unsigned n = segcnt[segi];
    const unsigned* seg = wl + (size_t)segi * SEGCAP;

    for (unsigned i = ((unsigned)threadIdx.x << 1) | (unsigned)half; i < n; i += 1024) {
        unsigned e = seg[i];
        int lt = (int)(e >> 4), g = (int)(e & 15u);
        int t = segi * 256 + lt;
        const float* ab = anc + (size_t)t * 5;
        const float* gb = ann + ((size_t)b * G_ + g) * 6;
        float v = rotated_iou_pair(ab, gb);
        unsigned long long ev = (unsigned long long)enc_f32(v);
        atomicMax(&rowMaxArg[t], (ev << 32) | (unsigned)(G_ - 1 - g));
        int aIdx = t & (A_ - 1);
        atomicMax(&cells[b * G_ + g], (ev << 32) | (0xFFFFFFFFu - (unsigned)aIdx));
    }
    __syncthreads();
    if (threadIdx.x < 32)
        partials[(size_t)blockIdx.x * 32 + threadIdx.x] = cells[threadIdx.x];
}

// ---------------------------------------------------------------------------
// Kernel 3: reduce per-block colmax partials + default candidate (0.0, a=0).
// For a valid gt every non-heavy column entry is exactly 0.0, so the column
// argmax is max(best heavy pair, (0.0, anchor 0)).
// ---------------------------------------------------------------------------
__global__ void colfinal_kernel(const unsigned long long* __restrict__ partials,
                                unsigned long long* __restrict__ packed) {
    __shared__ unsigned long long red[256];
    int cell = threadIdx.x & 31, chunk = threadIdx.x >> 5;  // 8 chunks x 32 blocks
    unsigned long long m = 0ull;
    for (int blk = chunk * (HB_ / 8); blk < (chunk + 1) * (HB_ / 8); ++blk) {
        unsigned long long v = partials[(size_t)blk * 32 + cell];
        if (v > m) m = v;
    }
    red[threadIdx.x] = m;
    __syncthreads();
    if (threadIdx.x < 32) {
        unsigned long long mm =
            ((unsigned long long)enc_f32(0.0f) << 32) | 0xFFFFFFFFu;  // (0.0, a=0)
        for (int c = 0; c < 8; ++c) {
            unsigned long long v = red[c * 32 + threadIdx.x];
            if (v > mm) mm = v;
        }
        packed[threadIdx.x] = mm;
    }
}

// ---------------------------------------------------------------------------
// Kernel 4: per-anchor loss; thresholds compared in encoded domain
// (enc is monotone). Block partial sums.
// ---------------------------------------------------------------------------
__global__ void loss_kernel(const float* __restrict__ cls_p,
                            const float* __restrict__ reg_p,
                            const float* __restrict__ anc,
                            const float* __restrict__ ann,
                            const unsigned long long* __restrict__ rowMaxArg,
                            const unsigned long long* __restrict__ packed,
                            float* __restrict__ pcls,
                            float* __restrict__ preg,
                            int* __restrict__ pnp) {
    int t = blockIdx.x * blockDim.x + threadIdx.x;  // over B_*A_
    int b = t >> 14;
    int a = t & (A_ - 1);

    unsigned long long rk = rowMaxArg[t];
    unsigned eh = (unsigned)(rk >> 32);             // enc(row max)
    int arg = (G_ - 1) - (int)(rk & 0xFu);          // first-g argmax

    // forced flag: some gt's column-argmax is this anchor, with colmax < 0.5
    bool forcedf = false;
#pragma unroll
    for (int g = 0; g < G_; ++g) {
        unsigned long long pk = packed[b * G_ + g];     // uniform -> scalar
        float lab = ann[((size_t)b * G_ + g) * 6 + 5];  // uniform -> scalar
        unsigned hi = (unsigned)(pk >> 32);
        unsigned ai = 0xFFFFFFFFu - (unsigned)pk;
        forcedf |= (lab != -1.0f) && (hi < ENC_HALF) && (ai == (unsigned)a);
    }

    bool pos = (eh >= ENC_HALF) || forcedf;
    const float* g6 = ann + ((size_t)b * G_ + arg) * 6;
    int cls = (int)g6[5];

    float csum = 0.f;
    if (pos || eh < ENC_04) {
        const float* pr = cls_p + (size_t)t * C_;
#pragma unroll
        for (int c = 0; c < C_; ++c) {
            float tgt = (pos && c == cls) ? 1.f : 0.f;
            float p = fminf(fmaxf(pr[c], 1e-4f), 1.f - 1e-4f);
            float af = (tgt == 1.f) ? 0.25f : 0.75f;
            float x = (tgt == 1.f) ? (1.f - p) : p;
            float fw = af * x * x;
            float bce = -(tgt * logf(p + 1e-6f) + (1.f - tgt) * logf(1.f - p + 1e-6f));
            csum += fw * bce;
        }
    }

    float rsum = 0.f;
    if (pos) {
        const float* ex = anc + (size_t)t * 5;
        const float* rp = reg_p + (size_t)t * 5;
        float ew = fmaxf(ex[2], 1.f), eh2 = fmaxf(ex[3], 1.f);
        float gw = fmaxf(g6[2], 1.f), gh = fmaxf(g6[3], 1.f);
        float tg[5];
        tg[0] = 10.f * (g6[0] - ex[0]) / ew;
        tg[1] = 10.f * (g6[1] - ex[1]) / eh2;
        tg[2] = 10.f * logf(gw / ew);
        tg[3] = 5.f * logf(gh / eh2);
        tg[4] = 15.f * (tanf(g6[4] * D2Rf) - tanf(ex[4] * D2Rf));
        const float BETAf = (float)(1.0 / 9.0);
#pragma unroll
        for (int i = 0; i < 5; ++i) {
            float d = fabsf(rp[i] - tg[i]);
            rsum += (d < BETAf) ? 0.5f * d * d / BETAf : d - 0.5f * BETAf;
        }
    }

    __shared__ float sc[256], sr[256];
    __shared__ int sp[256];
    sc[threadIdx.x] = csum; sr[threadIdx.x] = rsum; sp[threadIdx.x] = pos ? 1 : 0;
    __syncthreads();
    for (int s = 128; s > 0; s >>= 1) {
        if (threadIdx.x < s) {
            sc[threadIdx.x] += sc[threadIdx.x + s];
            sr[threadIdx.x] += sr[threadIdx.x + s];
            sp[threadIdx.x] += sp[threadIdx.x + s];
        }
        __syncthreads();
    }
    if (threadIdx.x == 0) {
        pcls[blockIdx.x] = sc[0];
        preg[blockIdx.x] = sr[0];
        pnp[blockIdx.x] = sp[0];
    }
}

// ---------------------------------------------------------------------------
// Kernel 5: final combine (deterministic ordered sum)
// ---------------------------------------------------------------------------
__global__ void final_kernel(const float* __restrict__ ann,
                             const float* __restrict__ pcls,
                             const float* __restrict__ preg,
                             const int* __restrict__ pnp,
                             float* __restrict__ out) {
    if (threadIdx.x == 0 && blockIdx.x == 0) {
        const int BPI = NBLK / B_;  // blocks per image = 64
        float cl[B_], rl[B_];
        for (int b = 0; b < B_; ++b) {
            float cs = 0.f, rs = 0.f; int np = 0;
            for (int i = 0; i < BPI; ++i) {
                cs += pcls[b * BPI + i];
                rs += preg[b * BPI + i];
                np += pnp[b * BPI + i];
            }
            bool has = false;
            for (int g = 0; g < G_; ++g)
                if (ann[((size_t)b * G_ + g) * 6 + 5] != -1.0f) has = true;
            float c_ = cs / fmaxf((float)np, 1.f);
            int d5 = np * 5; if (d5 < 1) d5 = 1;
            float r_ = (np > 0) ? rs / (float)d5 : 0.f;
            cl[b] = has ? c_ : 0.f;
            rl[b] = has ? r_ : 0.f;
        }
        float cm = 0.f, rm = 0.f;
        for (int b = 0; b < B_; ++b) { cm += cl[b]; rm += rl[b]; }
        out[0] = cm / (float)B_;
        out[1] = rm / (float)B_;
    }
}

// ---------------------------------------------------------------------------
extern "C" void kernel_launch(void* const* d_in, const int* in_sizes, int n_in,
                              void* d_out, int out_size, void* d_ws, size_t ws_size,
                              hipStream_t stream) {
    const float* cls_p = (const float*)d_in[0];   // (B,A,C)
    const float* reg_p = (const float*)d_in[1];   // (B,A,5)
    const float* anc   = (const float*)d_in[2];   // (B,A,5)
    const float* ann   = (const float*)d_in[3];   // (B,G,6)
    float* out = (float*)d_out;

    // workspace layout (everything fully rewritten each call; no memset)
    char* ws = (char*)d_ws;
    unsigned long long* packed    = (unsigned long long*)ws;               // 256 B
    unsigned long long* rowMaxArg = (unsigned long long*)(ws + 256);       // 256 KB
    unsigned long long* partials  = rowMaxArg + (size_t)B_ * A_;           // HB_*32*8 = 64 KB
    unsigned* segcnt = (unsigned*)(partials + (size_t)HB_ * 32);           // NBLK*4
    unsigned* wl     = segcnt + NBLK;                                      // NBLK*SEGCAP*4 = 2 MB
    float* pcls = (float*)(wl + (size_t)NBLK * SEGCAP);                    // NBLK
    float* preg = pcls + NBLK;
    int*   pnp  = (int*)(preg + NBLK);

    gate_kernel<<<NBLK, 256, 0, stream>>>(anc, ann, rowMaxArg, wl, segcnt);
    heavy_kernel<<<HB_, 512, 0, stream>>>(anc, ann, wl, segcnt, rowMaxArg, partials);
    colfinal_kernel<<<1, 256, 0, stream>>>(partials, packed);
    loss_kernel<<<NBLK, 256, 0, stream>>>(cls_p, reg_p, anc, ann,
                                          rowMaxArg, packed, pcls, preg, pnp);
    final_kernel<<<1, 64, 0, stream>>>(ann, pcls, preg, pnp, out);
}